// Round 5
// baseline (229.219 us; speedup 1.0000x reference)
//
#include <hip/hip_runtime.h>
#include <stdint.h>

// CSWin attention, MI355X/gfx950 — r14: 2-deep K prefetch, spill-free.
// Shapes: B=2, H=W=64, N=4, DIM=128, HEADS=4, HEAD_DIM=32, SPLIT=2.
// 64 windows x 4 heads, L=512 tokens, D=32. Grid 1024 = (window,head) x 4
// row-quarters; block 256 (4 waves); wave = 32 q-rows (2 m-tiles).
//
// r14: r13's lambda took float4* kb -> k0/k1 got ADDRESSED -> allocated in
// scratch (rule #20). Evidence: WRITE_SIZE 269MB (7.7x output), FETCH
// 152MB, VGPR stuck at 64 -> all "prefetch" traffic was private-segment
// spill. The 2-deep-prefetch theory never ran. Same schedule, macro body:
// k0/k1 are named arrays, every index compile-time constant, SROA keeps
// them in VGPRs (r12's nxt[8] pattern, duplicated).
// Theory unchanged from r13: all pipes <25% busy at ~60us -> wall time is
// serialized HBM/L2 round-trips; 2-deep prefetch makes stall per chunk
// max(0, latency - 2*body) instead of (latency - body); Q + K0/K1 issued
// before __syncthreads hide under the staging drain.
// Predicted: FETCH ~30MB / WRITE ~25MB (spill gone), VGPR ~96-120,
// dur ~45-52us if latency theory right (~60us falsifies it -> external
// limiter, restructure grid next), VALUBusy ~30%, conflicts ~754K.

typedef __bf16 bf16x8 __attribute__((ext_vector_type(8)));
typedef float f32x4 __attribute__((ext_vector_type(4)));
typedef float f32x2 __attribute__((ext_vector_type(2)));

#if __has_builtin(__builtin_amdgcn_exp2f)
#define EXP2F __builtin_amdgcn_exp2f
#else
#define EXP2F exp2f
#endif

union U4 { uint4 u; bf16x8 v; unsigned short s[8]; };

__device__ __forceinline__ float bf2f(unsigned short h){ union{unsigned u;float f;}x; x.u=((unsigned)h)<<16; return x.f; }

// f32 pair -> packed bf16 dword (lo in low half), RTNE. 1 instr.
__device__ __forceinline__ unsigned cvtpk(float lo, float hi){
  unsigned d;
  asm("v_cvt_pk_bf16_f32 %0, %1, %2" : "=v"(d) : "v"(lo), "v"(hi));
  return d;
}
__device__ __forceinline__ U4 pack8(float4 a, float4 b){
  U4 r;
  r.u.x = cvtpk(a.x, a.y); r.u.y = cvtpk(a.z, a.w);
  r.u.z = cvtpk(b.x, b.y); r.u.w = cvtpk(b.z, b.w);
  return r;
}

// permlane swap pair primitives (gfx950).
__device__ __forceinline__ void pls32(unsigned &a, unsigned &b){
#if __has_builtin(__builtin_amdgcn_permlane32_swap)
  auto r = __builtin_amdgcn_permlane32_swap(a, b, false, false);
  a = r[0]; b = r[1];
#else
  unsigned sa_ = __shfl_xor(a, 32), sb_ = __shfl_xor(b, 32);
  bool hi = ((threadIdx.x & 32) != 0);
  unsigned na = hi ? sb_ : a, nb = hi ? b : sa_;
  a = na; b = nb;
#endif
}
__device__ __forceinline__ void pls16(unsigned &a, unsigned &b){
#if __has_builtin(__builtin_amdgcn_permlane16_swap)
  auto r = __builtin_amdgcn_permlane16_swap(a, b, false, false);
  a = r[0]; b = r[1];
#else
  unsigned sa_ = __shfl_xor(a, 16), sb_ = __shfl_xor(b, 16);
  bool hi = ((threadIdx.x & 16) != 0);
  unsigned na = hi ? sb_ : a, nb = hi ? b : sa_;
  a = na; b = nb;
#endif
}

// In-register P transpose. Input: w[t][i] = packed P[q=n][k=16t+4*qd+{2i,2i+1}]
// Output A-frags: ap0 = P[row=n][k=qd*8..+7], ap1 = same for k+32.
__device__ __forceinline__ void xpose_p(const unsigned w[4][2], U4& ap0, U4& ap1)
{
  unsigned a0 = w[0][0], b0 = w[1][0]; pls32(a0, b0); pls16(a0, b0);
  unsigned a1 = w[0][1], b1 = w[1][1]; pls32(a1, b1); pls16(a1, b1);
  ap0.u.x = a0; ap0.u.y = a1; ap0.u.z = b0; ap0.u.w = b1;
  unsigned c0 = w[2][0], d0 = w[3][0]; pls32(c0, d0); pls16(c0, d0);
  unsigned c1 = w[2][1], d1 = w[3][1]; pls32(c1, d1); pls16(c1, d1);
  ap1.u.x = c0; ap1.u.y = c1; ap1.u.z = d0; ap1.u.w = d1;
}

#define C_SCALE 0.25506953149031837f  // (1/sqrt(32)) * log2(e)
#define M_SHIFT 20.0f                 // fixed log2-domain softmax shift

// Fused fixed-shift softmax + bf16 pack.
__device__ __forceinline__ void sm_pack(const f32x4* s, unsigned w[4][2], f32x2& l2)
{
  const f32x2 m2 = {-M_SHIFT, -M_SHIFT};
#pragma unroll
  for (int t = 0; t < 4; t++){
    f32x2 x0 = {s[t][0], s[t][1]};
    f32x2 x1 = {s[t][2], s[t][3]};
    f32x2 y0 = x0 * C_SCALE + m2;      // v_pk_fma_f32
    f32x2 y1 = x1 * C_SCALE + m2;
    float p0 = EXP2F(y0.x), p1 = EXP2F(y0.y);
    float p2 = EXP2F(y1.x), p3 = EXP2F(y1.y);
    l2 += (f32x2){p0, p1};
    l2 += (f32x2){p2, p3};
    w[t][0] = cvtpk(p0, p1);
    w[t][1] = cvtpk(p2, p3);
  }
}

// LDS: VT bf16 [32 ch][512 tok] swizzled, 1024B/row. Nothing else.
#define VT_OFF 0
#define LDS_BYTES 32768

// One chunk body. KB must be a NAMED float4[8] so every access is a
// compile-time-constant index (SROA -> VGPRs; r13's pointer param spilled).
#define CHUNK_BODY(CK, KB)                                                     \
  {                                                                            \
    const int ck_ = (CK);                                                      \
    U4 ak[4];                                                                  \
    _Pragma("unroll")                                                          \
    for (int t = 0; t < 4; t++) ak[t] = pack8(KB[2*t], KB[2*t+1]);             \
    if (ck_ < 6){                                                              \
      _Pragma("unroll")                                                        \
      for (int t = 0; t < 4; t++){                                             \
        const float* kp = kg + lane_base + (size_t)((ck_ + 2) * 4 + t) * 65536;\
        KB[2*t] = ((const float4*)kp)[0]; KB[2*t+1] = ((const float4*)kp)[1];  \
      }                                                                        \
    }                                                                          \
    const f32x4 zero = {0.f,0.f,0.f,0.f};                                      \
    f32x4 sa[4], sb[4];                                                        \
    _Pragma("unroll")                                                          \
    for (int t = 0; t < 4; t++){                                               \
      sa[t] = __builtin_amdgcn_mfma_f32_16x16x32_bf16(ak[t].v, bqa.v, zero, 0, 0, 0); \
      sb[t] = __builtin_amdgcn_mfma_f32_16x16x32_bf16(ak[t].v, bqb.v, zero, 0, 0, 0); \
    }                                                                          \
    if (ck_ == cka){                                                           \
      bool dq = (qd == (n >> 2));                                              \
      _Pragma("unroll")                                                        \
      for (int r = 0; r < 4; r++)                                              \
        if (dq && r != (n & 3)){ sa[ta][r] = -1e30f; sb[ta+1][r] = -1e30f; }   \
    }                                                                          \
    unsigned wA[4][2], wB[4][2];                                               \
    sm_pack(sa, wA, la2);                                                      \
    sm_pack(sb, wB, lb2);                                                      \
    const unsigned char* vr0 = smem + VT_OFF + n * 1024 + ck_ * 128;           \
    const unsigned char* vr1 = vr0 + 16 * 1024;                                \
    U4 bv00, bv01, bv10, bv11;                                                 \
    bv00.u = *(const uint4*)(vr0 + xb0);                                       \
    bv01.u = *(const uint4*)(vr0 + xb1);                                       \
    bv10.u = *(const uint4*)(vr1 + xb0);                                       \
    bv11.u = *(const uint4*)(vr1 + xb1);                                       \
    U4 apA0, apA1, apB0, apB1;                                                 \
    xpose_p(wA, apA0, apA1);                                                   \
    xpose_p(wB, apB0, apB1);                                                   \
    o0a = __builtin_amdgcn_mfma_f32_16x16x32_bf16(apA0.v, bv00.v, o0a, 0, 0, 0); \
    o0a = __builtin_amdgcn_mfma_f32_16x16x32_bf16(apA1.v, bv01.v, o0a, 0, 0, 0); \
    o1a = __builtin_amdgcn_mfma_f32_16x16x32_bf16(apA0.v, bv10.v, o1a, 0, 0, 0); \
    o1a = __builtin_amdgcn_mfma_f32_16x16x32_bf16(apA1.v, bv11.v, o1a, 0, 0, 0); \
    o0b = __builtin_amdgcn_mfma_f32_16x16x32_bf16(apB0.v, bv00.v, o0b, 0, 0, 0); \
    o0b = __builtin_amdgcn_mfma_f32_16x16x32_bf16(apB1.v, bv01.v, o0b, 0, 0, 0); \
    o1b = __builtin_amdgcn_mfma_f32_16x16x32_bf16(apB0.v, bv10.v, o1b, 0, 0, 0); \
    o1b = __builtin_amdgcn_mfma_f32_16x16x32_bf16(apB1.v, bv11.v, o1b, 0, 0, 0); \
  }

__global__ __launch_bounds__(256, 4) void cswin_attn_kernel(
    const float* __restrict__ qg,
    const float* __restrict__ kg,
    const float* __restrict__ vg,
    const float* __restrict__ cwg,
    float* __restrict__ outg)
{
  __shared__ __align__(16) unsigned char smem[LDS_BYTES];
  const int tid = threadIdx.x;
  const int lane = tid & 63;
  const int wave = tid >> 6;
  const int qd = lane >> 4;
  const int n  = lane & 15;

  // VT swizzle: in-row dword index ^= (row&7)<<2.
  const int swn = (n & 7) << 2;
  const int xb0 = ((4 * qd) ^ swn) << 2;   // byte off of swizzled dword 4qd
  const int xb1 = xb0 ^ 64;                // ... of dword 16+4qd

  const int bh = blockIdx.x & 255;
  const int q4 = blockIdx.x >> 8;     // row-quarter 0..3
  const int head = bh & 3;
  const int bw = bh >> 2;
  const int b  = bw >> 5;
  const int jj = bw & 31;

  // token l: offset = wbase + (l>>3)*32768 + ((l>>2)&1)*512 + (l&3)*128
  const size_t wbase = (size_t)b * 2097152 + (size_t)(jj * 2) * 512 + head * 32;

  // per-lane elem base for Q/K fragments (token tile*16+n, channels qd*8..+7)
  const size_t lane_base = wbase + (size_t)(n >> 3) * 32768 + (size_t)((n >> 2) & 1) * 512 +
                           (size_t)(n & 3) * 128 + qd * 8;

  const int row0  = q4 * 128 + wave * 32;
  const int tilea = row0 >> 4;          // even; m-tile B = tilea+1
  const int cka   = tilea >> 2;         // chunk holding both diag tiles
  const int ta    = tilea & 3;          // in-chunk tile idx of A's diag

  // ---- stage V -> VT bf16 (2 tokens per thread, packed pairwise) ----
  {
    int l0 = tid * 2;
    size_t off = wbase + (size_t)(l0 >> 3) * 32768 + (size_t)((l0 >> 2) & 1) * 512 + (l0 & 3) * 128;
    const float* p0 = vg + off;
    float v0[32], v1[32];
#pragma unroll
    for (int c = 0; c < 8; c++){
      float4 a = ((const float4*)p0)[c];
      v0[c*4+0]=a.x; v0[c*4+1]=a.y; v0[c*4+2]=a.z; v0[c*4+3]=a.w;
    }
#pragma unroll
    for (int c = 0; c < 8; c++){
      float4 a = ((const float4*)(p0 + 128))[c];
      v1[c*4+0]=a.x; v1[c*4+1]=a.y; v1[c*4+2]=a.z; v1[c*4+3]=a.w;
    }
    // logical dword col = tid (token pair 2*tid, 2*tid+1), row = d
#pragma unroll
    for (int d = 0; d < 32; d++)
      *(unsigned*)(smem + VT_OFF + d * 1024 + ((tid ^ ((d & 7) << 2)) << 2)) =
          cvtpk(v0[d], v1[d]);
  }

  // ---- issue Q raw + K chunk0/1 loads BEFORE the sync: their latency
  //      hides under the staging drain + __syncthreads ----
  float4 qra0, qra1, qrb0, qrb1;
  {
    const float* qa = qg + lane_base + (size_t)tilea * 65536;
    const float* qb = qa + 65536;
    qra0 = ((const float4*)qa)[0]; qra1 = ((const float4*)qa)[1];
    qrb0 = ((const float4*)qb)[0]; qrb1 = ((const float4*)qb)[1];
  }
  float4 k0[8], k1[8];
#pragma unroll
  for (int t = 0; t < 4; t++){
    const float* kp = kg + lane_base + (size_t)t * 65536;
    k0[2*t] = ((const float4*)kp)[0]; k0[2*t+1] = ((const float4*)kp)[1];
  }
#pragma unroll
  for (int t = 0; t < 4; t++){
    const float* kp = kg + lane_base + (size_t)(4 + t) * 65536;
    k1[2*t] = ((const float4*)kp)[0]; k1[2*t+1] = ((const float4*)kp)[1];
  }

  __syncthreads();

  U4 bqa = pack8(qra0, qra1);
  U4 bqb = pack8(qrb0, qrb1);

  f32x4 o0a={0,0,0,0}, o1a={0,0,0,0}, o0b={0,0,0,0}, o1b={0,0,0,0};
  f32x2 la2 = {0.f,0.f}, lb2 = {0.f,0.f};   // packed per-lane softmax sums

#pragma unroll 1
  for (int cc = 0; cc < 4; cc++){
    CHUNK_BODY(cc * 2,     k0)
    CHUNK_BODY(cc * 2 + 1, k1)
  }

  // ---- conv weights (global loads overlap the reductions below) ----
  float w9[2][9];
#pragma unroll
  for (int nt = 0; nt < 2; nt++){
    int c = head * 32 + nt * 16 + n;
#pragma unroll
    for (int t9 = 0; t9 < 9; t9++) w9[nt][t9] = cwg[c * 9 + t9];
  }

  // ---- final cross-lane l reduction (once, not per chunk) ----
  float la = la2.x + la2.y, lb = lb2.x + lb2.y;
  la += __shfl_xor(la, 16); la += __shfl_xor(la, 32);
  lb += __shfl_xor(lb, 16); lb += __shfl_xor(lb, 32);

  const float ila = 1.f / la, ilb = 1.f / lb;

  // ---- epilogue: compute both nt halves first, then store adjacently ----
#pragma unroll
  for (int mt = 0; mt < 2; mt++){
    const int m0 = row0 + mt * 16;
    const float ilv = mt ? ilb : ila;
    const f32x4 oo0 = mt ? o0b : o0a;
    const f32x4 oo1 = mt ? o1b : o1a;
    float il[4];
#pragma unroll
    for (int r = 0; r < 4; r++) il[r] = __shfl(ilv, qd * 4 + r);

    const int sp = (m0 >> 2) + qd;
    const int h_ = sp >> 1, w_ = sp & 1;

    float accs[2], cw2[2], vfs[2][4];
#pragma unroll
    for (int nt = 0; nt < 2; nt++){
      const int d = nt * 16 + n;
      const unsigned char* VTd = smem + VT_OFF + d * 1024;   // (d&7)==(n&7)
      float acc = 0.f;
#pragma unroll
      for (int dy = -1; dy <= 1; dy++){
        int h2 = h_ + dy;
        bool hv = (h2 >= 0) && (h2 <= 63);
        int h2c = hv ? h2 : h_;   // safe in-range address for masked lanes
#pragma unroll
        for (int wp = 0; wp < 2; wp++){
          bool valid = hv && !((dy == 0) && (wp == w_));
          int ti = (dy + 1) * 3 + 1 + wp - w_;
          int spn = h2c * 2 + wp;
          // S[spn][d] = sum of the 4 tokens at spatial pos spn
          uint2 sv = *(const uint2*)(VTd + (((2 * spn) ^ swn) << 2));
          float s = bf2f((unsigned short)(sv.x & 0xffff)) + bf2f((unsigned short)(sv.x >> 16))
                  + bf2f((unsigned short)(sv.y & 0xffff)) + bf2f((unsigned short)(sv.y >> 16));
          acc += (valid ? w9[nt][ti] : 0.f) * s;
        }
      }
      accs[nt] = acc;
      cw2[nt] = w9[nt][4];
      // V tokens m0+qd*4 .. +3 for the center-weight term (one uint2)
      uint2 vv4 = *(const uint2*)(VTd + ((((m0 >> 1) + 2 * qd) ^ swn) << 2));
      vfs[nt][0] = bf2f((unsigned short)(vv4.x & 0xffff));
      vfs[nt][1] = bf2f((unsigned short)(vv4.x >> 16));
      vfs[nt][2] = bf2f((unsigned short)(vv4.y & 0xffff));
      vfs[nt][3] = bf2f((unsigned short)(vv4.y >> 16));
    }

    const size_t obase = (size_t)b * 2097152 + (size_t)h_ * 32768 +
                         (size_t)(jj * 2 + w_) * 512 + head * 32;
#pragma unroll
    for (int r = 0; r < 4; r++){
      float r0 = oo0[r] * il[r] + accs[0] + cw2[0] * vfs[0][r];
      float r1 = oo1[r] * il[r] + accs[1] + cw2[1] * vfs[1][r];
      outg[obase + (size_t)r * 128 + n]      = r0;   // line half 1
      outg[obase + (size_t)r * 128 + 16 + n] = r1;   // line half 2 (adjacent)
    }
  }
}

extern "C" void kernel_launch(void* const* d_in, const int* in_sizes, int n_in,
                              void* d_out, int out_size, void* d_ws, size_t ws_size,
                              hipStream_t stream) {
  (void)in_sizes; (void)n_in; (void)d_ws; (void)ws_size; (void)out_size;
  cswin_attn_kernel<<<dim3(1024), dim3(256), 0, stream>>>(
      (const float*)d_in[0], (const float*)d_in[1], (const float*)d_in[2],
      (const float*)d_in[3], (float*)d_out);
}

// Round 6
// 134.106 us; speedup vs baseline: 1.7092x; 1.7092x over previous
//
#include <hip/hip_runtime.h>
#include <stdint.h>

// CSWin attention, MI355X/gfx950 — r15: 2-deep K prefetch with real registers.
// Shapes: B=2, H=W=64, N=4, DIM=128, HEADS=4, HEAD_DIM=32, SPLIT=2.
// 64 windows x 4 heads, L=512 tokens, D=32. Grid 1024; block 256 (4 waves);
// wave = 32 q-rows (2 m-tiles).
//
// r15: r13/r14 never tested the latency theory — launch_bounds(256,4) caps
// the allocator at 256/4 = 64 VGPRs (empirical: r9 arg=3 -> 72 alloc, cap 85;
// r10-14 arg=4 -> exactly 64), so the 64-reg K pipeline spilled to scratch
// (WRITE 346MB, VGPR pinned at 64). Changes:
//  * launch_bounds(256,2): cap 128. Peak pressure ~125 fits. HW occupancy
//    still 4 blocks/CU at <=128 VGPR (waves halve at 64/128/256 [m69]).
//  * 2-deep K prefetch kept (named k0/k1, macro body, const indices only).
//  * XCD-sibling grid remap: x=bid&7, q4=(bid>>3)&3, bh=((bid>>5)<<3)|x.
//    The 4 q4-siblings of a (window,head) share identical K/V/Q reads; same
//    bid%8 -> same XCD L2, co-resident -> loads become L2-hits (~200cy).
// Predicted: VGPR ~100-128, FETCH ~20-30MB, WRITE ~17-26MB, dur 40-50us if
// latency-bound. dur ~60us with clean counters falsifies -> TA/L1
// transaction-bound -> restructure K access next (all-heads LDS staging).

typedef __bf16 bf16x8 __attribute__((ext_vector_type(8)));
typedef float f32x4 __attribute__((ext_vector_type(4)));
typedef float f32x2 __attribute__((ext_vector_type(2)));

#if __has_builtin(__builtin_amdgcn_exp2f)
#define EXP2F __builtin_amdgcn_exp2f
#else
#define EXP2F exp2f
#endif

union U4 { uint4 u; bf16x8 v; unsigned short s[8]; };

__device__ __forceinline__ float bf2f(unsigned short h){ union{unsigned u;float f;}x; x.u=((unsigned)h)<<16; return x.f; }

// f32 pair -> packed bf16 dword (lo in low half), RTNE. 1 instr.
__device__ __forceinline__ unsigned cvtpk(float lo, float hi){
  unsigned d;
  asm("v_cvt_pk_bf16_f32 %0, %1, %2" : "=v"(d) : "v"(lo), "v"(hi));
  return d;
}
__device__ __forceinline__ U4 pack8(float4 a, float4 b){
  U4 r;
  r.u.x = cvtpk(a.x, a.y); r.u.y = cvtpk(a.z, a.w);
  r.u.z = cvtpk(b.x, b.y); r.u.w = cvtpk(b.z, b.w);
  return r;
}

// permlane swap pair primitives (gfx950).
__device__ __forceinline__ void pls32(unsigned &a, unsigned &b){
#if __has_builtin(__builtin_amdgcn_permlane32_swap)
  auto r = __builtin_amdgcn_permlane32_swap(a, b, false, false);
  a = r[0]; b = r[1];
#else
  unsigned sa_ = __shfl_xor(a, 32), sb_ = __shfl_xor(b, 32);
  bool hi = ((threadIdx.x & 32) != 0);
  unsigned na = hi ? sb_ : a, nb = hi ? b : sa_;
  a = na; b = nb;
#endif
}
__device__ __forceinline__ void pls16(unsigned &a, unsigned &b){
#if __has_builtin(__builtin_amdgcn_permlane16_swap)
  auto r = __builtin_amdgcn_permlane16_swap(a, b, false, false);
  a = r[0]; b = r[1];
#else
  unsigned sa_ = __shfl_xor(a, 16), sb_ = __shfl_xor(b, 16);
  bool hi = ((threadIdx.x & 16) != 0);
  unsigned na = hi ? sb_ : a, nb = hi ? b : sa_;
  a = na; b = nb;
#endif
}

// In-register P transpose. Input: w[t][i] = packed P[q=n][k=16t+4*qd+{2i,2i+1}]
// Output A-frags: ap0 = P[row=n][k=qd*8..+7], ap1 = same for k+32.
__device__ __forceinline__ void xpose_p(const unsigned w[4][2], U4& ap0, U4& ap1)
{
  unsigned a0 = w[0][0], b0 = w[1][0]; pls32(a0, b0); pls16(a0, b0);
  unsigned a1 = w[0][1], b1 = w[1][1]; pls32(a1, b1); pls16(a1, b1);
  ap0.u.x = a0; ap0.u.y = a1; ap0.u.z = b0; ap0.u.w = b1;
  unsigned c0 = w[2][0], d0 = w[3][0]; pls32(c0, d0); pls16(c0, d0);
  unsigned c1 = w[2][1], d1 = w[3][1]; pls32(c1, d1); pls16(c1, d1);
  ap1.u.x = c0; ap1.u.y = c1; ap1.u.z = d0; ap1.u.w = d1;
}

#define C_SCALE 0.25506953149031837f  // (1/sqrt(32)) * log2(e)
#define M_SHIFT 20.0f                 // fixed log2-domain softmax shift

// Fused fixed-shift softmax + bf16 pack.
__device__ __forceinline__ void sm_pack(const f32x4* s, unsigned w[4][2], f32x2& l2)
{
  const f32x2 m2 = {-M_SHIFT, -M_SHIFT};
#pragma unroll
  for (int t = 0; t < 4; t++){
    f32x2 x0 = {s[t][0], s[t][1]};
    f32x2 x1 = {s[t][2], s[t][3]};
    f32x2 y0 = x0 * C_SCALE + m2;      // v_pk_fma_f32
    f32x2 y1 = x1 * C_SCALE + m2;
    float p0 = EXP2F(y0.x), p1 = EXP2F(y0.y);
    float p2 = EXP2F(y1.x), p3 = EXP2F(y1.y);
    l2 += (f32x2){p0, p1};
    l2 += (f32x2){p2, p3};
    w[t][0] = cvtpk(p0, p1);
    w[t][1] = cvtpk(p2, p3);
  }
}

// LDS: VT bf16 [32 ch][512 tok] swizzled, 1024B/row. Nothing else.
#define VT_OFF 0
#define LDS_BYTES 32768

// One chunk body. KB must be a NAMED float4[8], const indices only.
#define CHUNK_BODY(CK, KB)                                                     \
  {                                                                            \
    const int ck_ = (CK);                                                      \
    U4 ak[4];                                                                  \
    _Pragma("unroll")                                                          \
    for (int t = 0; t < 4; t++) ak[t] = pack8(KB[2*t], KB[2*t+1]);             \
    if (ck_ < 6){                                                              \
      _Pragma("unroll")                                                        \
      for (int t = 0; t < 4; t++){                                             \
        const float* kp = kg + lane_base + (size_t)((ck_ + 2) * 4 + t) * 65536;\
        KB[2*t] = ((const float4*)kp)[0]; KB[2*t+1] = ((const float4*)kp)[1];  \
      }                                                                        \
    }                                                                          \
    const f32x4 zero = {0.f,0.f,0.f,0.f};                                      \
    f32x4 sa[4], sb[4];                                                        \
    _Pragma("unroll")                                                          \
    for (int t = 0; t < 4; t++){                                               \
      sa[t] = __builtin_amdgcn_mfma_f32_16x16x32_bf16(ak[t].v, bqa.v, zero, 0, 0, 0); \
      sb[t] = __builtin_amdgcn_mfma_f32_16x16x32_bf16(ak[t].v, bqb.v, zero, 0, 0, 0); \
    }                                                                          \
    if (ck_ == cka){                                                           \
      bool dq = (qd == (n >> 2));                                              \
      _Pragma("unroll")                                                        \
      for (int r = 0; r < 4; r++)                                              \
        if (dq && r != (n & 3)){ sa[ta][r] = -1e30f; sb[ta+1][r] = -1e30f; }   \
    }                                                                          \
    unsigned wA[4][2], wB[4][2];                                               \
    sm_pack(sa, wA, la2);                                                      \
    sm_pack(sb, wB, lb2);                                                      \
    const unsigned char* vr0 = smem + VT_OFF + n * 1024 + ck_ * 128;           \
    const unsigned char* vr1 = vr0 + 16 * 1024;                                \
    U4 bv00, bv01, bv10, bv11;                                                 \
    bv00.u = *(const uint4*)(vr0 + xb0);                                       \
    bv01.u = *(const uint4*)(vr0 + xb1);                                       \
    bv10.u = *(const uint4*)(vr1 + xb0);                                       \
    bv11.u = *(const uint4*)(vr1 + xb1);                                       \
    U4 apA0, apA1, apB0, apB1;                                                 \
    xpose_p(wA, apA0, apA1);                                                   \
    xpose_p(wB, apB0, apB1);                                                   \
    o0a = __builtin_amdgcn_mfma_f32_16x16x32_bf16(apA0.v, bv00.v, o0a, 0, 0, 0); \
    o0a = __builtin_amdgcn_mfma_f32_16x16x32_bf16(apA1.v, bv01.v, o0a, 0, 0, 0); \
    o1a = __builtin_amdgcn_mfma_f32_16x16x32_bf16(apA0.v, bv10.v, o1a, 0, 0, 0); \
    o1a = __builtin_amdgcn_mfma_f32_16x16x32_bf16(apA1.v, bv11.v, o1a, 0, 0, 0); \
    o0b = __builtin_amdgcn_mfma_f32_16x16x32_bf16(apB0.v, bv00.v, o0b, 0, 0, 0); \
    o0b = __builtin_amdgcn_mfma_f32_16x16x32_bf16(apB1.v, bv01.v, o0b, 0, 0, 0); \
    o1b = __builtin_amdgcn_mfma_f32_16x16x32_bf16(apB0.v, bv10.v, o1b, 0, 0, 0); \
    o1b = __builtin_amdgcn_mfma_f32_16x16x32_bf16(apB1.v, bv11.v, o1b, 0, 0, 0); \
  }

__global__ __launch_bounds__(256, 2) void cswin_attn_kernel(
    const float* __restrict__ qg,
    const float* __restrict__ kg,
    const float* __restrict__ vg,
    const float* __restrict__ cwg,
    float* __restrict__ outg)
{
  __shared__ __align__(16) unsigned char smem[LDS_BYTES];
  const int tid = threadIdx.x;
  const int lane = tid & 63;
  const int wave = tid >> 6;
  const int qd = lane >> 4;
  const int n  = lane & 15;

  // VT swizzle: in-row dword index ^= (row&7)<<2.
  const int swn = (n & 7) << 2;
  const int xb0 = ((4 * qd) ^ swn) << 2;   // byte off of swizzled dword 4qd
  const int xb1 = xb0 ^ 64;                // ... of dword 16+4qd

  // XCD-sibling remap: siblings (same window+head, q4=0..3) share bid%8
  // (same XCD L2) and are dispatched within 24 slots of each other.
  const int bid = blockIdx.x;
  const int bh = ((bid >> 5) << 3) | (bid & 7);   // (window,head) 0..255
  const int q4 = (bid >> 3) & 3;                  // row-quarter 0..3
  const int head = bh & 3;
  const int bw = bh >> 2;
  const int b  = bw >> 5;
  const int jj = bw & 31;

  // token l: offset = wbase + (l>>3)*32768 + ((l>>2)&1)*512 + (l&3)*128
  const size_t wbase = (size_t)b * 2097152 + (size_t)(jj * 2) * 512 + head * 32;

  // per-lane elem base for Q/K fragments (token tile*16+n, channels qd*8..+7)
  const size_t lane_base = wbase + (size_t)(n >> 3) * 32768 + (size_t)((n >> 2) & 1) * 512 +
                           (size_t)(n & 3) * 128 + qd * 8;

  const int row0  = q4 * 128 + wave * 32;
  const int tilea = row0 >> 4;          // even; m-tile B = tilea+1
  const int cka   = tilea >> 2;         // chunk holding both diag tiles
  const int ta    = tilea & 3;          // in-chunk tile idx of A's diag

  // ---- stage V -> VT bf16 (2 tokens per thread, packed pairwise) ----
  {
    int l0 = tid * 2;
    size_t off = wbase + (size_t)(l0 >> 3) * 32768 + (size_t)((l0 >> 2) & 1) * 512 + (l0 & 3) * 128;
    const float* p0 = vg + off;
    float v0[32], v1[32];
#pragma unroll
    for (int c = 0; c < 8; c++){
      float4 a = ((const float4*)p0)[c];
      v0[c*4+0]=a.x; v0[c*4+1]=a.y; v0[c*4+2]=a.z; v0[c*4+3]=a.w;
    }
#pragma unroll
    for (int c = 0; c < 8; c++){
      float4 a = ((const float4*)(p0 + 128))[c];
      v1[c*4+0]=a.x; v1[c*4+1]=a.y; v1[c*4+2]=a.z; v1[c*4+3]=a.w;
    }
    // logical dword col = tid (token pair 2*tid, 2*tid+1), row = d
#pragma unroll
    for (int d = 0; d < 32; d++)
      *(unsigned*)(smem + VT_OFF + d * 1024 + ((tid ^ ((d & 7) << 2)) << 2)) =
          cvtpk(v0[d], v1[d]);
  }

  // ---- issue Q raw + K chunk0/1 loads BEFORE the sync: their latency
  //      hides under the staging drain + __syncthreads ----
  float4 qra0, qra1, qrb0, qrb1;
  {
    const float* qa = qg + lane_base + (size_t)tilea * 65536;
    const float* qb = qa + 65536;
    qra0 = ((const float4*)qa)[0]; qra1 = ((const float4*)qa)[1];
    qrb0 = ((const float4*)qb)[0]; qrb1 = ((const float4*)qb)[1];
  }
  float4 k0[8], k1[8];
#pragma unroll
  for (int t = 0; t < 4; t++){
    const float* kp = kg + lane_base + (size_t)t * 65536;
    k0[2*t] = ((const float4*)kp)[0]; k0[2*t+1] = ((const float4*)kp)[1];
  }
#pragma unroll
  for (int t = 0; t < 4; t++){
    const float* kp = kg + lane_base + (size_t)(4 + t) * 65536;
    k1[2*t] = ((const float4*)kp)[0]; k1[2*t+1] = ((const float4*)kp)[1];
  }

  __syncthreads();

  U4 bqa = pack8(qra0, qra1);
  U4 bqb = pack8(qrb0, qrb1);

  f32x4 o0a={0,0,0,0}, o1a={0,0,0,0}, o0b={0,0,0,0}, o1b={0,0,0,0};
  f32x2 la2 = {0.f,0.f}, lb2 = {0.f,0.f};   // packed per-lane softmax sums

#pragma unroll 1
  for (int cc = 0; cc < 4; cc++){
    CHUNK_BODY(cc * 2,     k0)
    CHUNK_BODY(cc * 2 + 1, k1)
  }

  // ---- conv weights (global loads overlap the reductions below) ----
  float w9[2][9];
#pragma unroll
  for (int nt = 0; nt < 2; nt++){
    int c = head * 32 + nt * 16 + n;
#pragma unroll
    for (int t9 = 0; t9 < 9; t9++) w9[nt][t9] = cwg[c * 9 + t9];
  }

  // ---- final cross-lane l reduction (once, not per chunk) ----
  float la = la2.x + la2.y, lb = lb2.x + lb2.y;
  la += __shfl_xor(la, 16); la += __shfl_xor(la, 32);
  lb += __shfl_xor(lb, 16); lb += __shfl_xor(lb, 32);

  const float ila = 1.f / la, ilb = 1.f / lb;

  // ---- epilogue: compute both nt halves first, then store adjacently ----
#pragma unroll
  for (int mt = 0; mt < 2; mt++){
    const int m0 = row0 + mt * 16;
    const float ilv = mt ? ilb : ila;
    const f32x4 oo0 = mt ? o0b : o0a;
    const f32x4 oo1 = mt ? o1b : o1a;
    float il[4];
#pragma unroll
    for (int r = 0; r < 4; r++) il[r] = __shfl(ilv, qd * 4 + r);

    const int sp = (m0 >> 2) + qd;
    const int h_ = sp >> 1, w_ = sp & 1;

    float accs[2], cw2[2], vfs[2][4];
#pragma unroll
    for (int nt = 0; nt < 2; nt++){
      const int d = nt * 16 + n;
      const unsigned char* VTd = smem + VT_OFF + d * 1024;   // (d&7)==(n&7)
      float acc = 0.f;
#pragma unroll
      for (int dy = -1; dy <= 1; dy++){
        int h2 = h_ + dy;
        bool hv = (h2 >= 0) && (h2 <= 63);
        int h2c = hv ? h2 : h_;   // safe in-range address for masked lanes
#pragma unroll
        for (int wp = 0; wp < 2; wp++){
          bool valid = hv && !((dy == 0) && (wp == w_));
          int ti = (dy + 1) * 3 + 1 + wp - w_;
          int spn = h2c * 2 + wp;
          // S[spn][d] = sum of the 4 tokens at spatial pos spn
          uint2 sv = *(const uint2*)(VTd + (((2 * spn) ^ swn) << 2));
          float s = bf2f((unsigned short)(sv.x & 0xffff)) + bf2f((unsigned short)(sv.x >> 16))
                  + bf2f((unsigned short)(sv.y & 0xffff)) + bf2f((unsigned short)(sv.y >> 16));
          acc += (valid ? w9[nt][ti] : 0.f) * s;
        }
      }
      accs[nt] = acc;
      cw2[nt] = w9[nt][4];
      // V tokens m0+qd*4 .. +3 for the center-weight term (one uint2)
      uint2 vv4 = *(const uint2*)(VTd + ((((m0 >> 1) + 2 * qd) ^ swn) << 2));
      vfs[nt][0] = bf2f((unsigned short)(vv4.x & 0xffff));
      vfs[nt][1] = bf2f((unsigned short)(vv4.x >> 16));
      vfs[nt][2] = bf2f((unsigned short)(vv4.y & 0xffff));
      vfs[nt][3] = bf2f((unsigned short)(vv4.y >> 16));
    }

    const size_t obase = (size_t)b * 2097152 + (size_t)h_ * 32768 +
                         (size_t)(jj * 2 + w_) * 512 + head * 32;
#pragma unroll
    for (int r = 0; r < 4; r++){
      float r0 = oo0[r] * il[r] + accs[0] + cw2[0] * vfs[0][r];
      float r1 = oo1[r] * il[r] + accs[1] + cw2[1] * vfs[1][r];
      outg[obase + (size_t)r * 128 + n]      = r0;   // line half 1
      outg[obase + (size_t)r * 128 + 16 + n] = r1;   // line half 2 (adjacent)
    }
  }
}

extern "C" void kernel_launch(void* const* d_in, const int* in_sizes, int n_in,
                              void* d_out, int out_size, void* d_ws, size_t ws_size,
                              hipStream_t stream) {
  (void)in_sizes; (void)n_in; (void)d_ws; (void)ws_size; (void)out_size;
  cswin_attn_kernel<<<dim3(1024), dim3(256), 0, stream>>>(
      (const float*)d_in[0], (const float*)d_in[1], (const float*)d_in[2],
      (const float*)d_in[3], (float*)d_out);
}